// Round 1
// baseline (62.322 us; speedup 1.0000x reference)
//
#include <hip/hip_runtime.h>

// LinearAttention: B=4, H=8, L=4096, D=64, fp32 in/out.
// out = (elu1(Q) @ KV) * L / (elu1(Q)·Ksum + eps),
// KV = elu1(K)^T @ (V/L), Ksum = sum_l elu1(K).

#define LSEQ   4096
#define DDIM   64
#define NHEAD  32          // B*H
#define CHUNKS 32          // L-chunks per head in kernel 1
#define ROWSB  (LSEQ / CHUNKS)   // 128 rows per block
#define TILE   16          // rows staged in LDS per iteration
#define WSPH   (DDIM * DDIM + DDIM)  // 4160 floats per head in ws

__device__ __forceinline__ float fmap(float x) {
    // elu(x) + 1 = x+1 if x>0 else exp(x)
    return x > 0.0f ? (x + 1.0f) : __expf(x);
}

__device__ __forceinline__ void fma4(float4& a, float s, const float4& b) {
    a.x = fmaf(s, b.x, a.x);
    a.y = fmaf(s, b.y, a.y);
    a.z = fmaf(s, b.z, a.z);
    a.w = fmaf(s, b.w, a.w);
}

// ---------------- Kernel 1: KV[64][64] + Ksum[64] per head ----------------
// grid = NHEAD*CHUNKS blocks, 256 threads.
// Lane layout: dq = lane>>3 owns d = dq*8..+7 ; vq = lane&7 owns
// v = vq*4..+3 and 32+vq*4..+3. Each wave covers the FULL 64x64 KV;
// the 4 waves process disjoint rows, reduced in LDS at the end.
__global__ __launch_bounds__(256) void la_kv_kernel(
    const float* __restrict__ Kg, const float* __restrict__ Vg,
    float* __restrict__ ws)
{
    __shared__ float klds[TILE * DDIM];
    __shared__ float vlds[TILE * DDIM];
    __shared__ float red[WSPH];

    const int t    = threadIdx.x;
    const int wave = t >> 6;
    const int lane = t & 63;
    const int dq   = lane >> 3;
    const int vq   = lane & 7;

    const int bh    = blockIdx.x / CHUNKS;
    const int chunk = blockIdx.x % CHUNKS;
    const size_t base = (size_t)bh * LSEQ * DDIM + (size_t)chunk * ROWSB * DDIM;
    const float* Kb = Kg + base;
    const float* Vb = Vg + base;
    const float invL = 1.0f / (float)LSEQ;

    float acc[8][8];
    float ksum[8];
#pragma unroll
    for (int i = 0; i < 8; ++i) {
        ksum[i] = 0.0f;
#pragma unroll
        for (int j = 0; j < 8; ++j) acc[i][j] = 0.0f;
    }

    for (int tile = 0; tile < ROWSB / TILE; ++tile) {
        __syncthreads();
        // stage one 16x64 tile of K (feature-mapped) and V (pre-divided by L)
        float4 kx = ((const float4*)(Kb + tile * TILE * DDIM))[t];
        kx.x = fmap(kx.x); kx.y = fmap(kx.y); kx.z = fmap(kx.z); kx.w = fmap(kx.w);
        ((float4*)klds)[t] = kx;
        float4 vx = ((const float4*)(Vb + tile * TILE * DDIM))[t];
        vx.x *= invL; vx.y *= invL; vx.z *= invL; vx.w *= invL;
        ((float4*)vlds)[t] = vx;
        __syncthreads();

        // each wave processes 4 rows of the tile
#pragma unroll
        for (int r = 0; r < 4; ++r) {
            const int l = wave * 4 + r;
            const float4 ka = *(const float4*)(klds + l * DDIM + dq * 8);
            const float4 kb = *(const float4*)(klds + l * DDIM + dq * 8 + 4);
            const float4 va = *(const float4*)(vlds + l * DDIM + vq * 4);
            const float4 vb = *(const float4*)(vlds + l * DDIM + 32 + vq * 4);
            const float kk[8] = {ka.x, ka.y, ka.z, ka.w, kb.x, kb.y, kb.z, kb.w};
            const float vv[8] = {va.x, va.y, va.z, va.w, vb.x, vb.y, vb.z, vb.w};
#pragma unroll
            for (int i = 0; i < 8; ++i) {
                ksum[i] += kk[i];
#pragma unroll
                for (int j = 0; j < 8; ++j)
                    acc[i][j] = fmaf(kk[i], vv[j], acc[i][j]);
            }
        }
    }

    // sequential cross-wave reduce into LDS (wave w adds on its turn)
    for (int w = 0; w < 4; ++w) {
        __syncthreads();
        if (wave == w) {
#pragma unroll
            for (int i = 0; i < 8; ++i) {
                const int d = dq * 8 + i;
                float* p = red + d * DDIM + vq * 4;
                float4 lo = make_float4(acc[i][0], acc[i][1], acc[i][2], acc[i][3]);
                float4 hi = make_float4(acc[i][4], acc[i][5], acc[i][6], acc[i][7]);
                if (w != 0) {
                    const float4 plo = *(const float4*)p;
                    const float4 phi = *(const float4*)(p + 32);
                    lo.x += plo.x; lo.y += plo.y; lo.z += plo.z; lo.w += plo.w;
                    hi.x += phi.x; hi.y += phi.y; hi.z += phi.z; hi.w += phi.w;
                }
                *(float4*)p = lo;
                *(float4*)(p + 32) = hi;
            }
            if (vq == 0) {
                float* p = red + DDIM * DDIM + dq * 8;
                float4 s0 = make_float4(ksum[0], ksum[1], ksum[2], ksum[3]);
                float4 s1 = make_float4(ksum[4], ksum[5], ksum[6], ksum[7]);
                if (w != 0) {
                    const float4 p0 = *(const float4*)p;
                    const float4 p1 = *(const float4*)(p + 4);
                    s0.x += p0.x; s0.y += p0.y; s0.z += p0.z; s0.w += p0.w;
                    s1.x += p1.x; s1.y += p1.y; s1.z += p1.z; s1.w += p1.w;
                }
                *(float4*)p = s0;
                *(float4*)(p + 4) = s1;
            }
        }
    }
    __syncthreads();

    // one set of global fp32 atomics per block (native global_atomic_add_f32)
    float* dst = ws + (size_t)bh * WSPH;
    for (int i = t; i < WSPH; i += 256)
        unsafeAtomicAdd(dst + i, red[i]);
}

// ---------------- Kernel 2: out = (Qf @ KV) * L/(Qf·Ksum + eps) ----------------
// grid = NHEAD * (LSEQ/128) blocks, 256 threads; each block = 128 rows of one head.
#define QSTRIDE 68   // padded row stride (floats) to break bank alignment

__global__ __launch_bounds__(256) void la_out_kernel(
    const float* __restrict__ Qg, const float* __restrict__ ws,
    float* __restrict__ out)
{
    __shared__ float kvlds[DDIM * DDIM];
    __shared__ float ksl[DDIM];
    __shared__ float qlds[128 * QSTRIDE];
    __shared__ float zs[128];

    const int t    = threadIdx.x;
    const int bh   = blockIdx.x >> 5;
    const int tile = blockIdx.x & 31;
    const size_t base = (size_t)bh * LSEQ * DDIM + (size_t)tile * 128 * DDIM;
    const float* Qb = Qg + base;
    float* Ob = out + base;

    // stage KV (1024 float4) + Ksum (16 float4)
    const float4* wsrc = (const float4*)(ws + (size_t)bh * WSPH);
    for (int i = t; i < 1040; i += 256) {
        const float4 x = wsrc[i];
        if (i < 1024) ((float4*)kvlds)[i] = x;
        else          ((float4*)ksl)[i - 1024] = x;
    }

    // stage Q tile, feature-mapped, padded row stride
#pragma unroll
    for (int i = 0; i < 8; ++i) {
        const int o = t + i * 256;       // float4 index within 128x64 tile
        float4 q = ((const float4*)Qb)[o];
        q.x = fmap(q.x); q.y = fmap(q.y); q.z = fmap(q.z); q.w = fmap(q.w);
        const int row = o >> 4;
        const int c4  = o & 15;
        *(float4*)(qlds + row * QSTRIDE + c4 * 4) = q;
    }
    __syncthreads();

    // per-row zden: two threads per row, halves of d, shfl-combine
    {
        const int row  = t >> 1;
        const int half = t & 1;
        float s = 0.0f;
#pragma unroll
        for (int i = 0; i < 8; ++i) {
            const float4 q  = *(const float4*)(qlds + row * QSTRIDE + half * 32 + i * 4);
            const float4 ks = *(const float4*)(ksl + half * 32 + i * 4);
            s += q.x * ks.x + q.y * ks.y + q.z * ks.z + q.w * ks.w;
        }
        s += __shfl_xor(s, 1);
        if (half == 0) zs[row] = (float)LSEQ / (s + 1e-6f);
    }
    __syncthreads();

    // register-blocked GEMM: lane owns rows rg*4..+3, cols vq*4..+3 & 32+vq*4..+3
    const int vq = t & 7;
    const int rg = t >> 3;
    float4 accL[4], accH[4];
#pragma unroll
    for (int r = 0; r < 4; ++r) {
        accL[r] = make_float4(0.f, 0.f, 0.f, 0.f);
        accH[r] = make_float4(0.f, 0.f, 0.f, 0.f);
    }

    for (int d4 = 0; d4 < 16; ++d4) {
        float4 kvlo[4], kvhi[4];
#pragma unroll
        for (int i = 0; i < 4; ++i) {
            kvlo[i] = *(const float4*)(kvlds + (d4 * 4 + i) * DDIM + vq * 4);
            kvhi[i] = *(const float4*)(kvlds + (d4 * 4 + i) * DDIM + 32 + vq * 4);
        }
#pragma unroll
        for (int r = 0; r < 4; ++r) {
            const float4 q = *(const float4*)(qlds + (rg * 4 + r) * QSTRIDE + d4 * 4);
            fma4(accL[r], q.x, kvlo[0]);
            fma4(accL[r], q.y, kvlo[1]);
            fma4(accL[r], q.z, kvlo[2]);
            fma4(accL[r], q.w, kvlo[3]);
            fma4(accH[r], q.x, kvhi[0]);
            fma4(accH[r], q.y, kvhi[1]);
            fma4(accH[r], q.z, kvhi[2]);
            fma4(accH[r], q.w, kvhi[3]);
        }
    }

#pragma unroll
    for (int r = 0; r < 4; ++r) {
        const int row = rg * 4 + r;
        const float z = zs[row];
        float4 o = accL[r];
        o.x *= z; o.y *= z; o.z *= z; o.w *= z;
        *(float4*)(Ob + row * DDIM + vq * 4) = o;
        o = accH[r];
        o.x *= z; o.y *= z; o.z *= z; o.w *= z;
        *(float4*)(Ob + row * DDIM + 32 + vq * 4) = o;
    }
}

extern "C" void kernel_launch(void* const* d_in, const int* in_sizes, int n_in,
                              void* d_out, int out_size, void* d_ws, size_t ws_size,
                              hipStream_t stream) {
    const float* q = (const float*)d_in[0];
    const float* k = (const float*)d_in[1];
    const float* v = (const float*)d_in[2];
    float* o  = (float*)d_out;
    float* ws = (float*)d_ws;

    hipMemsetAsync(d_ws, 0, (size_t)NHEAD * WSPH * sizeof(float), stream);
    hipLaunchKernelGGL(la_kv_kernel, dim3(NHEAD * CHUNKS), dim3(256), 0, stream,
                       k, v, ws);
    hipLaunchKernelGGL(la_out_kernel, dim3(NHEAD * (LSEQ / 128)), dim3(256), 0, stream,
                       q, ws, o);
}

// Round 2
// 57.136 us; speedup vs baseline: 1.0908x; 1.0908x over previous
//
#include <hip/hip_runtime.h>

// LinearAttention: B=4, H=8, L=4096, D=64, fp32 in/out.
// out = (elu1(Q) @ KV) * L / (elu1(Q)·Ksum + eps),
// KV = elu1(K)^T @ (V/L), Ksum = sum_l elu1(K).
//
// 3 kernels, no atomics, no ws memset:
//   K1 : 1024 blocks (32 heads x 32 chunks) -> per-block partial KV+Ksum
//        written to a PRIVATE ws slot (overwrite semantics).
//   K1r: 160 blocks reduce 32 partials/head -> final KV+Ksum.
//   K2 : 1024 blocks compute out = (Qf@KV) * L/(Qf·Ksum+eps).

#define LSEQ   4096
#define DDIM   64
#define NHEAD  32          // B*H
#define CHUNKS 32          // L-chunks per head in kernel 1
#define ROWSB  (LSEQ / CHUNKS)   // 128 rows per block
#define TILE   16          // rows staged in LDS per iteration
#define WSPH   (DDIM * DDIM + DDIM)  // 4160 floats per partial / per head
#define WSPH4  (WSPH / 4)            // 1040 float4

__device__ __forceinline__ float fmap(float x) {
    // elu(x) + 1 = x+1 if x>0 else exp(x)
    return x > 0.0f ? (x + 1.0f) : __expf(x);
}

__device__ __forceinline__ void fma4(float4& a, float s, const float4& b) {
    a.x = fmaf(s, b.x, a.x);
    a.y = fmaf(s, b.y, a.y);
    a.z = fmaf(s, b.z, a.z);
    a.w = fmaf(s, b.w, a.w);
}

// ---------------- Kernel 1: partial KV[64][64] + Ksum[64] per (head,chunk) ----
__global__ __launch_bounds__(256) void la_kv_kernel(
    const float* __restrict__ Kg, const float* __restrict__ Vg,
    float* __restrict__ ws)
{
    __shared__ float klds[TILE * DDIM];
    __shared__ float vlds[TILE * DDIM];
    __shared__ float red[WSPH];

    const int t    = threadIdx.x;
    const int wave = t >> 6;
    const int lane = t & 63;
    const int dq   = lane >> 3;
    const int vq   = lane & 7;

    const int bh    = blockIdx.x / CHUNKS;
    const int chunk = blockIdx.x % CHUNKS;
    const size_t base = (size_t)bh * LSEQ * DDIM + (size_t)chunk * ROWSB * DDIM;
    const float* Kb = Kg + base;
    const float* Vb = Vg + base;
    const float invL = 1.0f / (float)LSEQ;

    float acc[8][8];
    float ksum[8];
#pragma unroll
    for (int i = 0; i < 8; ++i) {
        ksum[i] = 0.0f;
#pragma unroll
        for (int j = 0; j < 8; ++j) acc[i][j] = 0.0f;
    }

    for (int tile = 0; tile < ROWSB / TILE; ++tile) {
        __syncthreads();
        // stage one 16x64 tile of K (feature-mapped) and V (pre-divided by L)
        float4 kx = ((const float4*)(Kb + tile * TILE * DDIM))[t];
        kx.x = fmap(kx.x); kx.y = fmap(kx.y); kx.z = fmap(kx.z); kx.w = fmap(kx.w);
        ((float4*)klds)[t] = kx;
        float4 vx = ((const float4*)(Vb + tile * TILE * DDIM))[t];
        vx.x *= invL; vx.y *= invL; vx.z *= invL; vx.w *= invL;
        ((float4*)vlds)[t] = vx;
        __syncthreads();

        // each wave processes 4 rows of the tile; lane owns an 8d x 8v patch
#pragma unroll
        for (int r = 0; r < 4; ++r) {
            const int l = wave * 4 + r;
            const float4 ka = *(const float4*)(klds + l * DDIM + dq * 8);
            const float4 kb = *(const float4*)(klds + l * DDIM + dq * 8 + 4);
            const float4 va = *(const float4*)(vlds + l * DDIM + vq * 4);
            const float4 vb = *(const float4*)(vlds + l * DDIM + 32 + vq * 4);
            const float kk[8] = {ka.x, ka.y, ka.z, ka.w, kb.x, kb.y, kb.z, kb.w};
            const float vv[8] = {va.x, va.y, va.z, va.w, vb.x, vb.y, vb.z, vb.w};
#pragma unroll
            for (int i = 0; i < 8; ++i) {
                ksum[i] += kk[i];
#pragma unroll
                for (int j = 0; j < 8; ++j)
                    acc[i][j] = fmaf(kk[i], vv[j], acc[i][j]);
            }
        }
    }

    // sequential cross-wave reduce into LDS (wave w adds on its turn)
    for (int w = 0; w < 4; ++w) {
        __syncthreads();
        if (wave == w) {
#pragma unroll
            for (int i = 0; i < 8; ++i) {
                const int d = dq * 8 + i;
                float* p = red + d * DDIM + vq * 4;
                float4 lo = make_float4(acc[i][0], acc[i][1], acc[i][2], acc[i][3]);
                float4 hi = make_float4(acc[i][4], acc[i][5], acc[i][6], acc[i][7]);
                if (w != 0) {
                    const float4 plo = *(const float4*)p;
                    const float4 phi = *(const float4*)(p + 32);
                    lo.x += plo.x; lo.y += plo.y; lo.z += plo.z; lo.w += plo.w;
                    hi.x += phi.x; hi.y += phi.y; hi.z += phi.z; hi.w += phi.w;
                }
                *(float4*)p = lo;
                *(float4*)(p + 32) = hi;
            }
            if (vq == 0) {
                float* p = red + DDIM * DDIM + dq * 8;
                float4 s0 = make_float4(ksum[0], ksum[1], ksum[2], ksum[3]);
                float4 s1 = make_float4(ksum[4], ksum[5], ksum[6], ksum[7]);
                if (w != 0) {
                    const float4 p0 = *(const float4*)p;
                    const float4 p1 = *(const float4*)(p + 4);
                    s0.x += p0.x; s0.y += p0.y; s0.z += p0.z; s0.w += p0.w;
                    s1.x += p1.x; s1.y += p1.y; s1.z += p1.z; s1.w += p1.w;
                }
                *(float4*)p = s0;
                *(float4*)(p + 4) = s1;
            }
        }
    }
    __syncthreads();

    // coalesced store of the block's partial into its PRIVATE slot (no atomics)
    float4* dst = (float4*)(ws + (size_t)blockIdx.x * WSPH);
    const float4* src = (const float4*)red;
    for (int i = t; i < WSPH4; i += 256)
        dst[i] = src[i];
}

// ---------------- Kernel 1r: reduce 32 partials per head -> final KV+Ksum ----
// grid = NHEAD * 5 blocks, 256 threads; block (h,seg) reduces float4 slots
// [seg*208, seg*208+208) of head h (5*208 = 1040 = WSPH4).
__global__ __launch_bounds__(256) void la_reduce_kernel(
    const float* __restrict__ ws, float* __restrict__ kvout)
{
    const int h   = blockIdx.x / 5;
    const int seg = blockIdx.x % 5;
    const int t   = threadIdx.x;
    if (t >= 208) return;
    const int i4 = seg * 208 + t;

    const float4* base = (const float4*)(ws + (size_t)h * CHUNKS * WSPH) + i4;
    float4 acc = make_float4(0.f, 0.f, 0.f, 0.f);
#pragma unroll 8
    for (int p = 0; p < CHUNKS; ++p) {
        const float4 x = base[(size_t)p * WSPH4];
        acc.x += x.x; acc.y += x.y; acc.z += x.z; acc.w += x.w;
    }
    ((float4*)(kvout + (size_t)h * WSPH))[i4] = acc;
}

// ---------------- Kernel 2: out = (Qf @ KV) * L/(Qf·Ksum + eps) ----------------
#define QSTRIDE 68   // padded row stride (floats) to break bank alignment

__global__ __launch_bounds__(256) void la_out_kernel(
    const float* __restrict__ Qg, const float* __restrict__ kvin,
    float* __restrict__ out)
{
    __shared__ float kvlds[DDIM * DDIM];
    __shared__ float ksl[DDIM];
    __shared__ float qlds[128 * QSTRIDE];
    __shared__ float zs[128];

    const int t    = threadIdx.x;
    const int bh   = blockIdx.x >> 5;
    const int tile = blockIdx.x & 31;
    const size_t base = (size_t)bh * LSEQ * DDIM + (size_t)tile * 128 * DDIM;
    const float* Qb = Qg + base;
    float* Ob = out + base;

    // stage KV (1024 float4) + Ksum (16 float4)
    const float4* wsrc = (const float4*)(kvin + (size_t)bh * WSPH);
    for (int i = t; i < 1040; i += 256) {
        const float4 x = wsrc[i];
        if (i < 1024) ((float4*)kvlds)[i] = x;
        else          ((float4*)ksl)[i - 1024] = x;
    }

    // stage Q tile, feature-mapped, padded row stride
#pragma unroll
    for (int i = 0; i < 8; ++i) {
        const int o = t + i * 256;       // float4 index within 128x64 tile
        float4 q = ((const float4*)Qb)[o];
        q.x = fmap(q.x); q.y = fmap(q.y); q.z = fmap(q.z); q.w = fmap(q.w);
        const int row = o >> 4;
        const int c4  = o & 15;
        *(float4*)(qlds + row * QSTRIDE + c4 * 4) = q;
    }
    __syncthreads();

    // per-row zden: two threads per row, halves of d, shfl-combine
    {
        const int row  = t >> 1;
        const int half = t & 1;
        float s = 0.0f;
#pragma unroll
        for (int i = 0; i < 8; ++i) {
            const float4 q  = *(const float4*)(qlds + row * QSTRIDE + half * 32 + i * 4);
            const float4 ks = *(const float4*)(ksl + half * 32 + i * 4);
            s += q.x * ks.x + q.y * ks.y + q.z * ks.z + q.w * ks.w;
        }
        s += __shfl_xor(s, 1);
        if (half == 0) zs[row] = (float)LSEQ / (s + 1e-6f);
    }
    __syncthreads();

    // register-blocked GEMM: lane owns rows rg*4..+3, cols vq*4..+3 & 32+vq*4..+3
    const int vq = t & 7;
    const int rg = t >> 3;
    float4 accL[4], accH[4];
#pragma unroll
    for (int r = 0; r < 4; ++r) {
        accL[r] = make_float4(0.f, 0.f, 0.f, 0.f);
        accH[r] = make_float4(0.f, 0.f, 0.f, 0.f);
    }

    for (int d4 = 0; d4 < 16; ++d4) {
        float4 kvlo[4], kvhi[4];
#pragma unroll
        for (int i = 0; i < 4; ++i) {
            kvlo[i] = *(const float4*)(kvlds + (d4 * 4 + i) * DDIM + vq * 4);
            kvhi[i] = *(const float4*)(kvlds + (d4 * 4 + i) * DDIM + 32 + vq * 4);
        }
#pragma unroll
        for (int r = 0; r < 4; ++r) {
            const float4 q = *(const float4*)(qlds + (rg * 4 + r) * QSTRIDE + d4 * 4);
            fma4(accL[r], q.x, kvlo[0]);
            fma4(accL[r], q.y, kvlo[1]);
            fma4(accL[r], q.z, kvlo[2]);
            fma4(accL[r], q.w, kvlo[3]);
            fma4(accH[r], q.x, kvhi[0]);
            fma4(accH[r], q.y, kvhi[1]);
            fma4(accH[r], q.z, kvhi[2]);
            fma4(accH[r], q.w, kvhi[3]);
        }
    }

#pragma unroll
    for (int r = 0; r < 4; ++r) {
        const int row = rg * 4 + r;
        const float z = zs[row];
        float4 o = accL[r];
        o.x *= z; o.y *= z; o.z *= z; o.w *= z;
        *(float4*)(Ob + row * DDIM + vq * 4) = o;
        o = accH[r];
        o.x *= z; o.y *= z; o.z *= z; o.w *= z;
        *(float4*)(Ob + row * DDIM + 32 + vq * 4) = o;
    }
}

extern "C" void kernel_launch(void* const* d_in, const int* in_sizes, int n_in,
                              void* d_out, int out_size, void* d_ws, size_t ws_size,
                              hipStream_t stream) {
    const float* q = (const float*)d_in[0];
    const float* k = (const float*)d_in[1];
    const float* v = (const float*)d_in[2];
    float* o  = (float*)d_out;
    float* ws = (float*)d_ws;
    // ws layout: [0, 1024*WSPH) partials; [1024*WSPH, +32*WSPH) reduced KV.
    float* kvfinal = ws + (size_t)NHEAD * CHUNKS * WSPH;

    hipLaunchKernelGGL(la_kv_kernel, dim3(NHEAD * CHUNKS), dim3(256), 0, stream,
                       k, v, ws);
    hipLaunchKernelGGL(la_reduce_kernel, dim3(NHEAD * 5), dim3(256), 0, stream,
                       ws, kvfinal);
    hipLaunchKernelGGL(la_out_kernel, dim3(NHEAD * (LSEQ / 128)), dim3(256), 0, stream,
                       q, kvfinal, o);
}